// Round 2
// baseline (2133.200 us; speedup 1.0000x reference)
//
#include <hip/hip_runtime.h>
#include <hip/hip_bf16.h>

typedef _Float16 f16;
typedef _Float16 f16x8 __attribute__((ext_vector_type(8)));
typedef float    f32x4 __attribute__((ext_vector_type(4)));
typedef float    f32x8 __attribute__((ext_vector_type(8)));

__device__ __forceinline__ float silu_f(float x) {
    return x / (1.0f + __expf(-x));
}

// ---------------------------------------------------------------------------
// Weight prep: B1T[l][256][64] (node-GEMM B, P|Q columns), W2T[l][128][128],
// W3T[l][64][128] (transposed for MFMA B-fragments), w1c[l][128] (dist2 row).
// ---------------------------------------------------------------------------
__global__ void prep_kernel(const float* __restrict__ W1, const float* __restrict__ W2,
                            const float* __restrict__ W3, f16* __restrict__ B1T,
                            f16* __restrict__ W2T, f16* __restrict__ W3T,
                            float* __restrict__ w1c, int L, int total) {
    int idx = blockIdx.x * 256 + threadIdx.x;
    if (idx >= total) return;
    const int per = 16384 + 16384 + 8192 + 128;
    int l = idx / per, r = idx % per;
    const float* W1l = W1 + (size_t)l * 126 * 128;
    if (r < 16384) {                       // B1T: c in [0,256), k in [0,64)
        int c = r >> 6, k = r & 63;
        float v;
        if (c < 128) v = W1l[k * 128 + c];                       // P: xi @ W1[0:64]
        else v = (k >= 3) ? W1l[(64 + k - 3) * 128 + (c - 128)]  // Q: xj[3:] @ W1[64:125]
                          : 0.0f;
        B1T[(size_t)l * 16384 + r] = (f16)v;
    } else if (r < 32768) {                // W2T[n][k] = W2[k][n]
        int q = r - 16384, n = q >> 7, k = q & 127;
        W2T[(size_t)l * 16384 + q] = (f16)W2[(size_t)l * 16384 + k * 128 + n];
    } else if (r < 40960) {                // W3T[n][k] = W3[k][n]
        int q = r - 32768, n = q >> 7, k = q & 127;
        W3T[(size_t)l * 8192 + q] = (f16)W3[(size_t)l * 8192 + k * 64 + n];
    } else {                               // w1c = W1[125][:]
        int c = r - 40960;
        w1c[l * 128 + c] = W1l[125 * 128 + c];
    }
}

// ---------------------------------------------------------------------------
// CSR build: histogram over dst, 2-level exclusive scan, counting-sort scatter
// ---------------------------------------------------------------------------
__global__ void hist_kernel(const int* __restrict__ ei, int* __restrict__ deg, int E) {
    int i = blockIdx.x * 256 + threadIdx.x;
    if (i < E) atomicAdd(&deg[ei[E + i]], 1);
}

__global__ void scan_part(const int* __restrict__ deg, int* __restrict__ bsum, int N) {
    __shared__ int red[256];
    int t = threadIdx.x;
    int i = blockIdx.x * 256 + t;
    red[t] = (i < N) ? deg[i] : 0;
    __syncthreads();
    for (int s = 128; s > 0; s >>= 1) {
        if (t < s) red[t] += red[t + s];
        __syncthreads();
    }
    if (t == 0) bsum[blockIdx.x] = red[0];
}

__global__ void scan_mid(const int* __restrict__ bsum, int* __restrict__ boff, int nb) {
    __shared__ int sm[512];
    int t = threadIdx.x;
    int v = (t < nb) ? bsum[t] : 0;
    sm[t] = v;
    __syncthreads();
    for (int off = 1; off < 512; off <<= 1) {
        int a = (t >= off) ? sm[t - off] : 0;
        __syncthreads();
        sm[t] += a;
        __syncthreads();
    }
    if (t < nb) boff[t] = sm[t] - v;   // exclusive
}

__global__ void scan_final(const int* __restrict__ deg, const int* __restrict__ boff,
                           int* __restrict__ row_start, int N) {
    __shared__ int sm[256];
    int t = threadIdx.x;
    int i = blockIdx.x * 256 + t;
    int v = (i < N) ? deg[i] : 0;
    sm[t] = v;
    __syncthreads();
    for (int off = 1; off < 256; off <<= 1) {
        int a = (t >= off) ? sm[t - off] : 0;
        __syncthreads();
        sm[t] += a;
        __syncthreads();
    }
    if (i < N) row_start[i] = boff[blockIdx.x] + sm[t] - v;
}

__global__ void scatter_kernel(const int* __restrict__ ei, const int* __restrict__ row_start,
                               int* __restrict__ cursor, int* __restrict__ srcs,
                               int* __restrict__ dsts, int E) {
    int i = blockIdx.x * 256 + threadIdx.x;
    if (i < E) {
        int d = ei[E + i];
        int p = row_start[d] + atomicAdd(&cursor[d], 1);
        srcs[p] = ei[i];
        dsts[p] = d;
    }
}

// ---------------------------------------------------------------------------
// Node kernel: PQ[n][0:128] = x[n]@W1a + b1 ; PQ[n][128:256] = x[n,3:]@W1b
// Also emits C[n] = coords for dist2. MFMA 16x16x32 f16, 64-node tiles.
// ---------------------------------------------------------------------------
__global__ __launch_bounds__(256, 3) void node_kernel(
    const float* __restrict__ x, const f16* __restrict__ B1T,
    const float* __restrict__ b1, f16* __restrict__ PQ,
    float4* __restrict__ C, int N, int ntiles) {
    __shared__ f16 b1t[256 * 72];   // padded stride 72 (2-way bank aliasing only)
    const int tid = threadIdx.x;
    const int w = tid >> 6, lane = tid & 63, lm = lane & 15, kg = lane >> 4;

    for (int i = tid; i < 256 * 64; i += 256)
        b1t[(i >> 6) * 72 + (i & 63)] = B1T[i];
    __syncthreads();

    for (int tile = blockIdx.x; tile < ntiles; tile += gridDim.x) {
        const int base = tile * 64;
        int ar = base + w * 16 + lm;
        if (ar >= N) ar = N - 1;

        f16x8 afrag[2];
#pragma unroll
        for (int ks = 0; ks < 2; ks++) {
            f32x8 v = *(const f32x8*)(x + (size_t)ar * 64 + ks * 32 + kg * 8);
            f16x8 h;
#pragma unroll
            for (int j = 0; j < 8; j++) h[j] = (f16)v[j];
            afrag[ks] = h;
        }

        f32x4 acc[16];
#pragma unroll
        for (int nb = 0; nb < 16; nb++) acc[nb] = (f32x4){0.f, 0.f, 0.f, 0.f};
#pragma unroll
        for (int ks = 0; ks < 2; ks++)
#pragma unroll
            for (int nb = 0; nb < 16; nb++) {
                f16x8 b = *(const f16x8*)&b1t[(nb * 16 + lm) * 72 + ks * 32 + kg * 8];
                acc[nb] = __builtin_amdgcn_mfma_f32_16x16x32_f16(afrag[ks], b, acc[nb], 0, 0, 0);
            }

#pragma unroll
        for (int nb = 0; nb < 16; nb++) {
            int col = nb * 16 + lm;
            float bias = (col < 128) ? b1[col] : 0.0f;
#pragma unroll
            for (int reg = 0; reg < 4; reg++) {
                int orow = base + w * 16 + kg * 4 + reg;
                if (orow < N) PQ[(size_t)orow * 256 + col] = (f16)(acc[nb][reg] + bias);
            }
        }
        if (tid < 64) {
            int n = base + tid;
            if (n < N) {
                const float* xr = x + (size_t)n * 64;
                C[n] = make_float4(xr[0], xr[1], xr[2], 0.0f);
            }
        }
    }
}

// ---------------------------------------------------------------------------
// Edge kernel v2: 64-edge dst-sorted tiles, barrier-free main loop.
//   h1 = silu(P[dst]+Q[src]+dist2*w1c)  -> A-frags in registers
//   h2 = silu(h1@W2 + b2)               -> W2T in swizzled LDS (32KB)
//   GEMM2 in 4 k-quarters through a 4.6KB wave-private transpose buffer
//   m  = silu(h2@W3 + b3)               -> in-register segmented reduce,
//                                          <=4 atomics/lane (dst-sorted runs)
// LDS total 36.6KB -> 4 blocks/CU, 16 waves/CU.
// ---------------------------------------------------------------------------
__global__ __launch_bounds__(256, 4) void edge_kernel(
    const f16* __restrict__ PQ, const float4* __restrict__ C,
    const int* __restrict__ srcs, const int* __restrict__ dsts,
    const f16* __restrict__ W2T, const f16* __restrict__ W3T,
    const float* __restrict__ w1c, const float* __restrict__ b2,
    const float* __restrict__ b3, float* __restrict__ xout,
    int E, int ntiles) {
    __shared__ f16 w2t[128 * 128];     // 32KB, XOR-swizzled
    __shared__ f16 tb[4 * 16 * 36];    // 4.5KB: per-wave h2-transpose slices

    const int tid = threadIdx.x;
    const int w = tid >> 6, lane = tid & 63, lm = lane & 15, kg = lane >> 4;

    for (int i = tid; i < 128 * 128; i += 256) {
        int n = i >> 7, k = i & 127;
        w2t[n * 128 + (((k >> 3) ^ (n & 15)) << 3) + (k & 7)] = W2T[i];
    }
    __syncthreads();

    f16* tbuf = tb + w * (16 * 36);

    // hoist biases into registers (reused every tile)
    float bias2[8], bias3[4];
#pragma unroll
    for (int nb = 0; nb < 8; nb++) bias2[nb] = b2[nb * 16 + lm];
#pragma unroll
    for (int nb = 0; nb < 4; nb++) bias3[nb] = b3[nb * 16 + lm];

    for (int tile = blockIdx.x; tile < ntiles; tile += gridDim.x) {
        const int base = tile * 64;

        int er = base + w * 16 + lm;
        if (er >= E) er = E - 1;
        const int s = srcs[er], d = dsts[er];

        // ---- issue ALL long-latency loads up front ----
        const f16* pd = PQ + (size_t)d * 256;
        const f16* ps = PQ + (size_t)s * 256 + 128;
        f16x8 pv[4], qv[4];
        f32x8 wv[4];
#pragma unroll
        for (int ks = 0; ks < 4; ks++) {
            int off = ks * 32 + kg * 8;
            pv[ks] = *(const f16x8*)(pd + off);
            qv[ks] = *(const f16x8*)(ps + off);
            wv[ks] = *(const f32x8*)(w1c + off);
        }
        float4 cs = C[s], cd = C[d];

        // dst ids for this lane's 4 owned output rows (sequential, L1-hot)
        const int r0 = base + kg * 4 + w * 16;
        int dr0 = (r0     < E) ? dsts[r0]     : -1;
        int dr1 = (r0 + 1 < E) ? dsts[r0 + 1] : -1;
        int dr2 = (r0 + 2 < E) ? dsts[r0 + 2] : -1;
        int dr3 = (r0 + 3 < E) ? dsts[r0 + 3] : -1;

        float dx = cs.x - cd.x, dy = cs.y - cd.y, dz = cs.z - cd.z;
        float dist2 = dx * dx + dy * dy + dz * dz;

        // ---- h1 into A fragments ----
        f16x8 afrag[4];
#pragma unroll
        for (int ks = 0; ks < 4; ks++) {
            f16x8 h;
#pragma unroll
            for (int j = 0; j < 8; j++) {
                float v = (float)pv[ks][j] + (float)qv[ks][j] + dist2 * wv[ks][j];
                h[j] = (f16)silu_f(v);
            }
            afrag[ks] = h;
        }

        // ---- GEMM1: h1 @ W2 ----
        f32x4 acc1[8];
#pragma unroll
        for (int nb = 0; nb < 8; nb++) acc1[nb] = (f32x4){0.f, 0.f, 0.f, 0.f};
#pragma unroll
        for (int ks = 0; ks < 4; ks++)
#pragma unroll
            for (int nb = 0; nb < 8; nb++) {
                int n = nb * 16 + lm;
                f16x8 b = *(const f16x8*)&w2t[n * 128 + (((ks * 4 + kg) ^ (n & 15)) << 3)];
                acc1[nb] = __builtin_amdgcn_mfma_f32_16x16x32_f16(afrag[ks], b, acc1[nb], 0, 0, 0);
            }

        // ---- GEMM2 in 4 k-quarters (32 h2-dims each) via wave-private tbuf ----
        f32x4 acc2[4];
#pragma unroll
        for (int nb2 = 0; nb2 < 4; nb2++) acc2[nb2] = (f32x4){0.f, 0.f, 0.f, 0.f};
#pragma unroll
        for (int kq = 0; kq < 4; kq++) {
#pragma unroll
            for (int nn = 0; nn < 2; nn++) {
                int nb = kq * 2 + nn;
#pragma unroll
                for (int reg = 0; reg < 4; reg++)
                    tbuf[(kg * 4 + reg) * 36 + nn * 16 + lm] =
                        (f16)silu_f(acc1[nb][reg] + bias2[nb]);
            }
            f16x8 a2 = *(const f16x8*)&tbuf[lm * 36 + kg * 8];
#pragma unroll
            for (int nb2 = 0; nb2 < 4; nb2++) {
                f16x8 b = *(const f16x8*)(W3T + (size_t)(nb2 * 16 + lm) * 128 +
                                          kq * 32 + kg * 8);
                acc2[nb2] = __builtin_amdgcn_mfma_f32_16x16x32_f16(a2, b, acc2[nb2], 0, 0, 0);
            }
        }

        // ---- m = silu(acc2+b3); segmented in-register reduce over 4 rows ----
#pragma unroll
        for (int nb2 = 0; nb2 < 4; nb2++) {
            int c = nb2 * 16 + lm;
            float bias = bias3[nb2];
            float v0 = (dr0 >= 0) ? silu_f(acc2[nb2][0] + bias) : 0.0f;
            float v1 = (dr1 >= 0) ? silu_f(acc2[nb2][1] + bias) : 0.0f;
            float v2 = (dr2 >= 0) ? silu_f(acc2[nb2][2] + bias) : 0.0f;
            float v3 = (dr3 >= 0) ? silu_f(acc2[nb2][3] + bias) : 0.0f;
            float* xc = xout + c;
            if (dr0 != dr1) {
                if (dr0 >= 0) atomicAdd(xc + (size_t)dr0 * 64, v0);
            } else v1 += v0;
            if (dr1 != dr2) {
                if (dr1 >= 0) atomicAdd(xc + (size_t)dr1 * 64, v1);
            } else v2 += v1;
            if (dr2 != dr3) {
                if (dr2 >= 0) atomicAdd(xc + (size_t)dr2 * 64, v2);
            } else v3 += v2;
            if (dr3 >= 0) atomicAdd(xc + (size_t)dr3 * 64, v3);
        }
    }
}

// ---------------------------------------------------------------------------
// Pooling: per-graph add/mean/max over contiguous node ranges (batch = n*G//N)
// ---------------------------------------------------------------------------
__global__ void pool_kernel(const float* __restrict__ xf, const float* __restrict__ u,
                            float* __restrict__ pooled, int N, int G) {
    int g = blockIdx.x;
    int t = threadIdx.x;
    int ch = t & 63, sub = t >> 6;
    long long n0 = ((long long)g * N + G - 1) / G;
    long long n1 = ((long long)(g + 1) * N + G - 1) / G;
    float sm = 0.f, mx = -3.0e38f;
    for (long long n = n0 + sub; n < n1; n += 4) {
        float v = xf[n * 64 + ch];
        sm += v;
        mx = fmaxf(mx, v);
    }
    __shared__ float ssum[256], smax[256];
    ssum[t] = sm;
    smax[t] = mx;
    __syncthreads();
    if (sub == 0) {
        float a = ssum[ch] + ssum[64 + ch] + ssum[128 + ch] + ssum[192 + ch];
        float m = fmaxf(fmaxf(smax[ch], smax[64 + ch]), fmaxf(smax[128 + ch], smax[192 + ch]));
        float cnt = (float)(n1 - n0);
        pooled[g * 194 + ch] = a;
        pooled[g * 194 + 64 + ch] = a / fmaxf(cnt, 1.f);
        pooled[g * 194 + 128 + ch] = m;
    }
    if (t == 0) {
        pooled[g * 194 + 192] = u[g * 2];
        pooled[g * 194 + 193] = u[g * 2 + 1];
    }
}

// ---------------------------------------------------------------------------
// Readout head (fp32): [G,194]@[194,64] silu, @[64,64] silu, @[64,2]
// ---------------------------------------------------------------------------
__global__ void head_kernel(const float* __restrict__ pooled,
                            const float* __restrict__ LW1, const float* __restrict__ Lb1,
                            const float* __restrict__ LW2, const float* __restrict__ Lb2,
                            const float* __restrict__ LW3, const float* __restrict__ Lb3,
                            float* __restrict__ out, int G) {
    int g = blockIdx.x, t = threadIdx.x;
    __shared__ float pl[194];
    __shared__ float hl[64];
    for (int k = t; k < 194; k += 64) pl[k] = pooled[g * 194 + k];
    __syncthreads();
    float a = Lb1[t];
    for (int k = 0; k < 194; k++) a += pl[k] * LW1[k * 64 + t];
    a = silu_f(a);
    hl[t] = a;
    __syncthreads();
    float b = Lb2[t];
    for (int k = 0; k < 64; k++) b += hl[k] * LW2[k * 64 + t];
    b = silu_f(b);
    __syncthreads();
    hl[t] = b;
    __syncthreads();
    if (t < 2) {
        float c = Lb3[t];
        for (int k = 0; k < 64; k++) c += hl[k] * LW3[k * 2 + t];
        out[g * 2 + t] = c;
    }
}

// ---------------------------------------------------------------------------
extern "C" void kernel_launch(void* const* d_in, const int* in_sizes, int n_in,
                              void* d_out, int out_size, void* d_ws, size_t ws_size,
                              hipStream_t stream) {
    const float* x   = (const float*)d_in[0];
    const float* u   = (const float*)d_in[1];
    const int*   ei  = (const int*)d_in[2];
    const float* W1  = (const float*)d_in[4];
    const float* b1  = (const float*)d_in[5];
    const float* W2  = (const float*)d_in[6];
    const float* b2  = (const float*)d_in[7];
    const float* W3  = (const float*)d_in[8];
    const float* b3  = (const float*)d_in[9];
    const float* LW1 = (const float*)d_in[10];
    const float* Lb1 = (const float*)d_in[11];
    const float* LW2 = (const float*)d_in[12];
    const float* Lb2 = (const float*)d_in[13];
    const float* LW3 = (const float*)d_in[14];
    const float* Lb3 = (const float*)d_in[15];

    const int N = in_sizes[0] / 64;
    const int G = in_sizes[1] / 2;
    const int E = in_sizes[2] / 2;
    const int L = in_sizes[4] / (126 * 128);

    char* ws = (char*)d_ws;
    size_t off = 0;
    auto alloc = [&](size_t bytes) -> char* {
        char* p = ws + off;
        off += (bytes + 511) & ~(size_t)511;
        return p;
    };
    f16*    PQ     = (f16*)alloc((size_t)N * 256 * 2);
    float4* C      = (float4*)alloc((size_t)N * 16);
    float*  x1     = (float*)alloc((size_t)N * 64 * 4);
    float*  x2     = (float*)alloc((size_t)N * 64 * 4);
    int*    srcs   = (int*)alloc((size_t)E * 4);
    int*    dsts   = (int*)alloc((size_t)E * 4);
    int*    deg    = (int*)alloc((size_t)N * 4);
    int*    rowst  = (int*)alloc((size_t)N * 4);
    int*    cursor = (int*)alloc((size_t)N * 4);
    int*    bsum   = (int*)alloc(4096);
    int*    boff   = (int*)alloc(4096);
    f16*    B1T    = (f16*)alloc((size_t)L * 256 * 64 * 2);
    f16*    W2T    = (f16*)alloc((size_t)L * 128 * 128 * 2);
    f16*    W3T    = (f16*)alloc((size_t)L * 64 * 128 * 2);
    float*  w1c    = (float*)alloc((size_t)L * 128 * 4);
    float*  pooled = (float*)alloc((size_t)G * 194 * 4);
    (void)ws_size;
    (void)n_in;
    (void)out_size;

    hipMemsetAsync(deg, 0, (size_t)N * 4, stream);
    hipMemsetAsync(cursor, 0, (size_t)N * 4, stream);
    hipMemsetAsync(x1, 0, (size_t)N * 64 * 4, stream);
    hipMemsetAsync(x2, 0, (size_t)N * 64 * 4, stream);

    {
        int total = L * (16384 + 16384 + 8192 + 128);
        prep_kernel<<<(total + 255) / 256, 256, 0, stream>>>(W1, W2, W3, B1T, W2T, W3T, w1c, L, total);
    }
    hist_kernel<<<(E + 255) / 256, 256, 0, stream>>>(ei, deg, E);
    int NB = (N + 255) / 256;
    scan_part<<<NB, 256, 0, stream>>>(deg, bsum, N);
    scan_mid<<<1, 512, 0, stream>>>(bsum, boff, NB);
    scan_final<<<NB, 256, 0, stream>>>(deg, boff, rowst, N);
    scatter_kernel<<<(E + 255) / 256, 256, 0, stream>>>(ei, rowst, cursor, srcs, dsts, E);

    const float* xcur = x;
    const int etiles = (E + 63) / 64;
    const int ntiles_node = (N + 63) / 64;
    for (int l = 0; l < L; l++) {
        node_kernel<<<768, 256, 0, stream>>>(xcur, B1T + (size_t)l * 16384, b1 + l * 128,
                                             PQ, C, N, ntiles_node);
        float* xo = (l & 1) ? x2 : x1;
        edge_kernel<<<1024, 256, 0, stream>>>(PQ, C, srcs, dsts,
                                              W2T + (size_t)l * 16384, W3T + (size_t)l * 8192,
                                              w1c + l * 128, b2 + l * 128, b3 + l * 64,
                                              xo, E, etiles);
        xcur = xo;
    }
    pool_kernel<<<G, 256, 0, stream>>>(xcur, u, pooled, N, G);
    head_kernel<<<G, 64, 0, stream>>>(pooled, LW1, Lb1, LW2, Lb2, LW3, Lb3, (float*)d_out, G);
}

// Round 3
// 2106.682 us; speedup vs baseline: 1.0126x; 1.0126x over previous
//
#include <hip/hip_runtime.h>
#include <hip/hip_bf16.h>

typedef _Float16 f16;
typedef _Float16 f16x8 __attribute__((ext_vector_type(8)));
typedef float    f32x4 __attribute__((ext_vector_type(4)));
typedef float    f32x8 __attribute__((ext_vector_type(8)));

__device__ __forceinline__ float silu_f(float x) {
    // x * 1/(1+e^-x) via v_rcp_f32 (~1e-5 rel err, far below f16 rounding)
    return x * __builtin_amdgcn_rcpf(1.0f + __expf(-x));
}

// ---------------------------------------------------------------------------
// Weight prep: B1T[l][256][64] (node-GEMM B, P|Q columns), W2T[l][128][128],
// W3T[l][64][128] (transposed for MFMA B-fragments), w1c[l][128] f16 (dist2 row)
// ---------------------------------------------------------------------------
__global__ void prep_kernel(const float* __restrict__ W1, const float* __restrict__ W2,
                            const float* __restrict__ W3, f16* __restrict__ B1T,
                            f16* __restrict__ W2T, f16* __restrict__ W3T,
                            f16* __restrict__ w1c, int L, int total) {
    int idx = blockIdx.x * 256 + threadIdx.x;
    if (idx >= total) return;
    const int per = 16384 + 16384 + 8192 + 128;
    int l = idx / per, r = idx % per;
    const float* W1l = W1 + (size_t)l * 126 * 128;
    if (r < 16384) {                       // B1T: c in [0,256), k in [0,64)
        int c = r >> 6, k = r & 63;
        float v;
        if (c < 128) v = W1l[k * 128 + c];                       // P: xi @ W1[0:64]
        else v = (k >= 3) ? W1l[(64 + k - 3) * 128 + (c - 128)]  // Q: xj[3:] @ W1[64:125]
                          : 0.0f;
        B1T[(size_t)l * 16384 + r] = (f16)v;
    } else if (r < 32768) {                // W2T[n][k] = W2[k][n]
        int q = r - 16384, n = q >> 7, k = q & 127;
        W2T[(size_t)l * 16384 + q] = (f16)W2[(size_t)l * 16384 + k * 128 + n];
    } else if (r < 40960) {                // W3T[n][k] = W3[k][n]
        int q = r - 32768, n = q >> 7, k = q & 127;
        W3T[(size_t)l * 8192 + q] = (f16)W3[(size_t)l * 8192 + k * 64 + n];
    } else {                               // w1c = W1[125][:]
        int c = r - 40960;
        w1c[l * 128 + c] = (f16)W1l[125 * 128 + c];
    }
}

// ---------------------------------------------------------------------------
// CSR build: histogram over dst, 2-level exclusive scan, counting-sort scatter
// ---------------------------------------------------------------------------
__global__ void hist_kernel(const int* __restrict__ ei, int* __restrict__ deg, int E) {
    int i = blockIdx.x * 256 + threadIdx.x;
    if (i < E) atomicAdd(&deg[ei[E + i]], 1);
}

__global__ void scan_part(const int* __restrict__ deg, int* __restrict__ bsum, int N) {
    __shared__ int red[256];
    int t = threadIdx.x;
    int i = blockIdx.x * 256 + t;
    red[t] = (i < N) ? deg[i] : 0;
    __syncthreads();
    for (int s = 128; s > 0; s >>= 1) {
        if (t < s) red[t] += red[t + s];
        __syncthreads();
    }
    if (t == 0) bsum[blockIdx.x] = red[0];
}

__global__ void scan_mid(const int* __restrict__ bsum, int* __restrict__ boff, int nb) {
    __shared__ int sm[512];
    int t = threadIdx.x;
    int v = (t < nb) ? bsum[t] : 0;
    sm[t] = v;
    __syncthreads();
    for (int off = 1; off < 512; off <<= 1) {
        int a = (t >= off) ? sm[t - off] : 0;
        __syncthreads();
        sm[t] += a;
        __syncthreads();
    }
    if (t < nb) boff[t] = sm[t] - v;   // exclusive
}

__global__ void scan_final(const int* __restrict__ deg, const int* __restrict__ boff,
                           int* __restrict__ row_start, int N) {
    __shared__ int sm[256];
    int t = threadIdx.x;
    int i = blockIdx.x * 256 + t;
    int v = (i < N) ? deg[i] : 0;
    sm[t] = v;
    __syncthreads();
    for (int off = 1; off < 256; off <<= 1) {
        int a = (t >= off) ? sm[t - off] : 0;
        __syncthreads();
        sm[t] += a;
        __syncthreads();
    }
    if (i < N) row_start[i] = boff[blockIdx.x] + sm[t] - v;
}

__global__ void scatter_kernel(const int* __restrict__ ei, const int* __restrict__ row_start,
                               int* __restrict__ cursor, int* __restrict__ srcs,
                               int* __restrict__ dsts, int E) {
    int i = blockIdx.x * 256 + threadIdx.x;
    if (i < E) {
        int d = ei[E + i];
        int p = row_start[d] + atomicAdd(&cursor[d], 1);
        srcs[p] = ei[i];
        dsts[p] = d;
    }
}

// ---------------------------------------------------------------------------
// Node kernel: PQ[n][0:128] = x[n]@W1a + b1 ; PQ[n][128:256] = x[n,3:]@W1b
// Also emits C[n] = coords for dist2. MFMA 16x16x32 f16, 64-node tiles.
// ---------------------------------------------------------------------------
__global__ __launch_bounds__(256, 3) void node_kernel(
    const float* __restrict__ x, const f16* __restrict__ B1T,
    const float* __restrict__ b1, f16* __restrict__ PQ,
    float4* __restrict__ C, int N, int ntiles) {
    __shared__ f16 b1t[256 * 72];   // padded stride 72 (2-way bank aliasing only)
    const int tid = threadIdx.x;
    const int w = tid >> 6, lane = tid & 63, lm = lane & 15, kg = lane >> 4;

    for (int i = tid; i < 256 * 64; i += 256)
        b1t[(i >> 6) * 72 + (i & 63)] = B1T[i];
    __syncthreads();

    for (int tile = blockIdx.x; tile < ntiles; tile += gridDim.x) {
        const int base = tile * 64;
        int ar = base + w * 16 + lm;
        if (ar >= N) ar = N - 1;

        f16x8 afrag[2];
#pragma unroll
        for (int ks = 0; ks < 2; ks++) {
            f32x8 v = *(const f32x8*)(x + (size_t)ar * 64 + ks * 32 + kg * 8);
            f16x8 h;
#pragma unroll
            for (int j = 0; j < 8; j++) h[j] = (f16)v[j];
            afrag[ks] = h;
        }

        f32x4 acc[16];
#pragma unroll
        for (int nb = 0; nb < 16; nb++) acc[nb] = (f32x4){0.f, 0.f, 0.f, 0.f};
#pragma unroll
        for (int ks = 0; ks < 2; ks++)
#pragma unroll
            for (int nb = 0; nb < 16; nb++) {
                f16x8 b = *(const f16x8*)&b1t[(nb * 16 + lm) * 72 + ks * 32 + kg * 8];
                acc[nb] = __builtin_amdgcn_mfma_f32_16x16x32_f16(afrag[ks], b, acc[nb], 0, 0, 0);
            }

#pragma unroll
        for (int nb = 0; nb < 16; nb++) {
            int col = nb * 16 + lm;
            float bias = (col < 128) ? b1[col] : 0.0f;
#pragma unroll
            for (int reg = 0; reg < 4; reg++) {
                int orow = base + w * 16 + kg * 4 + reg;
                if (orow < N) PQ[(size_t)orow * 256 + col] = (f16)(acc[nb][reg] + bias);
            }
        }
        if (tid < 64) {
            int n = base + tid;
            if (n < N) {
                const float* xr = x + (size_t)n * 64;
                C[n] = make_float4(xr[0], xr[1], xr[2], 0.0f);
            }
        }
    }
}

// ---------------------------------------------------------------------------
// Edge kernel v3: 64-edge dst-sorted tiles, software-pipelined gathers.
//   h1 = silu(P[dst]+Q[src]+dist2*w1c)  -> A-frags in registers (cheap silu)
//   h2 = silu(h1@W2 + b2)               -> W2T in swizzled LDS (32KB)
//   GEMM2 in 4 k-quarters via wave-private 4.5KB transpose slices
//   m  -> f16 LDS region [64][66]; tile-wide segmented scan:
//         interior dst-runs (exclusive owner) -> plain store
//         boundary runs (touch row 0 / rows-1) -> atomicAdd  (~3M atomics total)
// LDS 32+4.5+8.25 = 44.8KB -> 3 blocks/CU. Next tile's srcs/dsts/PQ/C loads
// are issued mid-compute to hide gather latency.
// ---------------------------------------------------------------------------
__global__ __launch_bounds__(256, 3) void edge_kernel(
    const f16* __restrict__ PQ, const float4* __restrict__ C,
    const int* __restrict__ srcs, const int* __restrict__ dsts,
    const f16* __restrict__ W2T, const f16* __restrict__ W3T,
    const f16* __restrict__ w1c, const float* __restrict__ b2,
    const float* __restrict__ b3, float* __restrict__ xout,
    int E, int ntiles) {
    __shared__ f16 w2t[128 * 128];     // 32KB, XOR-swizzled
    __shared__ f16 tb[4 * 16 * 36];    // 4.5KB: per-wave h2-transpose slices
    __shared__ f16 mreg[64 * 66];      // 8.25KB: m tile (padded stride 66)

    const int tid = threadIdx.x;
    const int w = tid >> 6, lane = tid & 63, lm = lane & 15, kg = lane >> 4;

    for (int i = tid; i < 128 * 128; i += 256) {
        int n = i >> 7, k = i & 127;
        w2t[n * 128 + (((k >> 3) ^ (n & 15)) << 3) + (k & 7)] = W2T[i];
    }

    // loop-invariant hoists
    f16x8 wvh[4];
#pragma unroll
    for (int ks = 0; ks < 4; ks++) wvh[ks] = *(const f16x8*)(w1c + ks * 32 + kg * 8);
    float bias2[8], bias3[4];
#pragma unroll
    for (int nb = 0; nb < 8; nb++) bias2[nb] = b2[nb * 16 + lm];
#pragma unroll
    for (int nb = 0; nb < 4; nb++) bias3[nb] = b3[nb * 16 + lm];
    __syncthreads();

    f16* tbuf = tb + w * (16 * 36);
    const int gstride = gridDim.x;

    // ---- prologue: issue tile-0 gathers ----
    int tile = blockIdx.x;
    int er = tile * 64 + w * 16 + lm;
    if (er >= E) er = E - 1;
    int s = srcs[er], d = dsts[er];
    f16x8 pv[4], qv[4];
    float4 cs, cd;
    {
        const f16* pd = PQ + (size_t)d * 256;
        const f16* ps = PQ + (size_t)s * 256 + 128;
#pragma unroll
        for (int ks = 0; ks < 4; ks++) {
            int off = ks * 32 + kg * 8;
            pv[ks] = *(const f16x8*)(pd + off);
            qv[ks] = *(const f16x8*)(ps + off);
        }
        cs = C[s];
        cd = C[d];
    }

    while (tile < ntiles) {
        const int base = tile * 64;
        const int rows = min(64, E - base);
        const int ntile = tile + gstride;

        // ---- prefetch next tile's indices (issue before heavy compute) ----
        int er2 = ntile * 64 + w * 16 + lm;
        if (ntile >= ntiles) er2 = er;
        if (er2 >= E) er2 = E - 1;
        const int s2 = srcs[er2], d2 = dsts[er2];

        float dx = cs.x - cd.x, dy = cs.y - cd.y, dz = cs.z - cd.z;
        float dist2 = dx * dx + dy * dy + dz * dz;

        // ---- h1 into A fragments ----
        f16x8 afrag[4];
#pragma unroll
        for (int ks = 0; ks < 4; ks++) {
            f16x8 h;
#pragma unroll
            for (int j = 0; j < 8; j++) {
                float v = (float)pv[ks][j] + (float)qv[ks][j] + dist2 * (float)wvh[ks][j];
                h[j] = (f16)silu_f(v);
            }
            afrag[ks] = h;
        }

        // ---- GEMM1: h1 @ W2 ----
        f32x4 acc1[8];
#pragma unroll
        for (int nb = 0; nb < 8; nb++) acc1[nb] = (f32x4){0.f, 0.f, 0.f, 0.f};
#pragma unroll
        for (int ks = 0; ks < 4; ks++)
#pragma unroll
            for (int nb = 0; nb < 8; nb++) {
                int n = nb * 16 + lm;
                f16x8 b = *(const f16x8*)&w2t[n * 128 + (((ks * 4 + kg) ^ (n & 15)) << 3)];
                acc1[nb] = __builtin_amdgcn_mfma_f32_16x16x32_f16(afrag[ks], b, acc1[nb], 0, 0, 0);
            }

        // ---- issue next tile's gathers now (hidden behind GEMM2 + scan) ----
        f16x8 pv2[4], qv2[4];
        float4 cs2, cd2;
        {
            const f16* pd2 = PQ + (size_t)d2 * 256;
            const f16* ps2 = PQ + (size_t)s2 * 256 + 128;
#pragma unroll
            for (int ks = 0; ks < 4; ks++) {
                int off = ks * 32 + kg * 8;
                pv2[ks] = *(const f16x8*)(pd2 + off);
                qv2[ks] = *(const f16x8*)(ps2 + off);
            }
            cs2 = C[s2];
            cd2 = C[d2];
        }

        // ---- GEMM2 in 4 k-quarters via wave-private tbuf ----
        f32x4 acc2[4];
#pragma unroll
        for (int nb2 = 0; nb2 < 4; nb2++) acc2[nb2] = (f32x4){0.f, 0.f, 0.f, 0.f};
#pragma unroll
        for (int kq = 0; kq < 4; kq++) {
#pragma unroll
            for (int nn = 0; nn < 2; nn++) {
                int nb = kq * 2 + nn;
#pragma unroll
                for (int reg = 0; reg < 4; reg++)
                    tbuf[(kg * 4 + reg) * 36 + nn * 16 + lm] =
                        (f16)silu_f(acc1[nb][reg] + bias2[nb]);
            }
            f16x8 a2 = *(const f16x8*)&tbuf[lm * 36 + kg * 8];
#pragma unroll
            for (int nb2 = 0; nb2 < 4; nb2++) {
                f16x8 b = *(const f16x8*)(W3T + (size_t)(nb2 * 16 + lm) * 128 +
                                          kq * 32 + kg * 8);
                acc2[nb2] = __builtin_amdgcn_mfma_f32_16x16x32_f16(a2, b, acc2[nb2], 0, 0, 0);
            }
        }

        // ---- m = silu(acc2+b3) -> f16 LDS region ----
#pragma unroll
        for (int nb2 = 0; nb2 < 4; nb2++) {
            int c = nb2 * 16 + lm;
            float bias = bias3[nb2];
#pragma unroll
            for (int reg = 0; reg < 4; reg++) {
                int r = w * 16 + kg * 4 + reg;
                mreg[r * 66 + c] = (f16)silu_f(acc2[nb2][reg] + bias);
            }
        }
        __syncthreads();

        // ---- tile-wide segmented scan over sorted dst ----
        {
            const int ch = tid & 63;
            const int rg = tid >> 6;
            for (int it = 0; it < 16; it++) {
                int r = it * 4 + rg;
                if (r < rows) {
                    int dr = dsts[base + r];
                    bool head = (r == 0) || (dsts[base + r - 1] != dr);
                    if (head) {
                        float sum = (float)mreg[r * 66 + ch];
                        int rr = r + 1;
                        while (rr < rows && dsts[base + rr] == dr) {
                            sum += (float)mreg[rr * 66 + ch];
                            rr++;
                        }
                        float* p = xout + (size_t)dr * 64 + ch;
                        if (r == 0 || rr == rows) atomicAdd(p, sum);  // may span tiles
                        else *p = sum;                                 // exclusive owner
                    }
                }
            }
        }
        __syncthreads();   // scan reads done before next tile overwrites mreg

        // ---- rotate pipeline registers ----
        tile = ntile;
        er = er2; s = s2; d = d2;
#pragma unroll
        for (int ks = 0; ks < 4; ks++) { pv[ks] = pv2[ks]; qv[ks] = qv2[ks]; }
        cs = cs2;
        cd = cd2;
    }
}

// ---------------------------------------------------------------------------
// Pooling: per-graph add/mean/max over contiguous node ranges (batch = n*G//N)
// ---------------------------------------------------------------------------
__global__ void pool_kernel(const float* __restrict__ xf, const float* __restrict__ u,
                            float* __restrict__ pooled, int N, int G) {
    int g = blockIdx.x;
    int t = threadIdx.x;
    int ch = t & 63, sub = t >> 6;
    long long n0 = ((long long)g * N + G - 1) / G;
    long long n1 = ((long long)(g + 1) * N + G - 1) / G;
    float sm = 0.f, mx = -3.0e38f;
    for (long long n = n0 + sub; n < n1; n += 4) {
        float v = xf[n * 64 + ch];
        sm += v;
        mx = fmaxf(mx, v);
    }
    __shared__ float ssum[256], smax[256];
    ssum[t] = sm;
    smax[t] = mx;
    __syncthreads();
    if (sub == 0) {
        float a = ssum[ch] + ssum[64 + ch] + ssum[128 + ch] + ssum[192 + ch];
        float m = fmaxf(fmaxf(smax[ch], smax[64 + ch]), fmaxf(smax[128 + ch], smax[192 + ch]));
        float cnt = (float)(n1 - n0);
        pooled[g * 194 + ch] = a;
        pooled[g * 194 + 64 + ch] = a / fmaxf(cnt, 1.f);
        pooled[g * 194 + 128 + ch] = m;
    }
    if (t == 0) {
        pooled[g * 194 + 192] = u[g * 2];
        pooled[g * 194 + 193] = u[g * 2 + 1];
    }
}

// ---------------------------------------------------------------------------
// Readout head (fp32): [G,194]@[194,64] silu, @[64,64] silu, @[64,2]
// ---------------------------------------------------------------------------
__global__ void head_kernel(const float* __restrict__ pooled,
                            const float* __restrict__ LW1, const float* __restrict__ Lb1,
                            const float* __restrict__ LW2, const float* __restrict__ Lb2,
                            const float* __restrict__ LW3, const float* __restrict__ Lb3,
                            float* __restrict__ out, int G) {
    int g = blockIdx.x, t = threadIdx.x;
    __shared__ float pl[194];
    __shared__ float hl[64];
    for (int k = t; k < 194; k += 64) pl[k] = pooled[g * 194 + k];
    __syncthreads();
    float a = Lb1[t];
    for (int k = 0; k < 194; k++) a += pl[k] * LW1[k * 64 + t];
    a = a / (1.0f + __expf(-a));
    hl[t] = a;
    __syncthreads();
    float b = Lb2[t];
    for (int k = 0; k < 64; k++) b += hl[k] * LW2[k * 64 + t];
    b = b / (1.0f + __expf(-b));
    __syncthreads();
    hl[t] = b;
    __syncthreads();
    if (t < 2) {
        float c = Lb3[t];
        for (int k = 0; k < 64; k++) c += hl[k] * LW3[k * 2 + t];
        out[g * 2 + t] = c;
    }
}

// ---------------------------------------------------------------------------
extern "C" void kernel_launch(void* const* d_in, const int* in_sizes, int n_in,
                              void* d_out, int out_size, void* d_ws, size_t ws_size,
                              hipStream_t stream) {
    const float* x   = (const float*)d_in[0];
    const float* u   = (const float*)d_in[1];
    const int*   ei  = (const int*)d_in[2];
    const float* W1  = (const float*)d_in[4];
    const float* b1  = (const float*)d_in[5];
    const float* W2  = (const float*)d_in[6];
    const float* b2  = (const float*)d_in[7];
    const float* W3  = (const float*)d_in[8];
    const float* b3  = (const float*)d_in[9];
    const float* LW1 = (const float*)d_in[10];
    const float* Lb1 = (const float*)d_in[11];
    const float* LW2 = (const float*)d_in[12];
    const float* Lb2 = (const float*)d_in[13];
    const float* LW3 = (const float*)d_in[14];
    const float* Lb3 = (const float*)d_in[15];

    const int N = in_sizes[0] / 64;
    const int G = in_sizes[1] / 2;
    const int E = in_sizes[2] / 2;
    const int L = in_sizes[4] / (126 * 128);

    char* ws = (char*)d_ws;
    size_t off = 0;
    auto alloc = [&](size_t bytes) -> char* {
        char* p = ws + off;
        off += (bytes + 511) & ~(size_t)511;
        return p;
    };
    f16*    PQ     = (f16*)alloc((size_t)N * 256 * 2);
    float4* C      = (float4*)alloc((size_t)N * 16);
    float*  x1     = (float*)alloc((size_t)N * 64 * 4);
    float*  x2     = (float*)alloc((size_t)N * 64 * 4);
    int*    srcs   = (int*)alloc((size_t)E * 4);
    int*    dsts   = (int*)alloc((size_t)E * 4);
    int*    deg    = (int*)alloc((size_t)N * 4);
    int*    rowst  = (int*)alloc((size_t)N * 4);
    int*    cursor = (int*)alloc((size_t)N * 4);
    int*    bsum   = (int*)alloc(4096);
    int*    boff   = (int*)alloc(4096);
    f16*    B1T    = (f16*)alloc((size_t)L * 256 * 64 * 2);
    f16*    W2T    = (f16*)alloc((size_t)L * 128 * 128 * 2);
    f16*    W3T    = (f16*)alloc((size_t)L * 64 * 128 * 2);
    f16*    w1c    = (f16*)alloc((size_t)L * 128 * 2);
    float*  pooled = (float*)alloc((size_t)G * 194 * 4);
    (void)ws_size;
    (void)n_in;
    (void)out_size;

    hipMemsetAsync(deg, 0, (size_t)N * 4, stream);
    hipMemsetAsync(cursor, 0, (size_t)N * 4, stream);
    hipMemsetAsync(x1, 0, (size_t)N * 64 * 4, stream);
    hipMemsetAsync(x2, 0, (size_t)N * 64 * 4, stream);

    {
        int total = L * (16384 + 16384 + 8192 + 128);
        prep_kernel<<<(total + 255) / 256, 256, 0, stream>>>(W1, W2, W3, B1T, W2T, W3T, w1c, L, total);
    }
    hist_kernel<<<(E + 255) / 256, 256, 0, stream>>>(ei, deg, E);
    int NB = (N + 255) / 256;
    scan_part<<<NB, 256, 0, stream>>>(deg, bsum, N);
    scan_mid<<<1, 512, 0, stream>>>(bsum, boff, NB);
    scan_final<<<NB, 256, 0, stream>>>(deg, boff, rowst, N);
    scatter_kernel<<<(E + 255) / 256, 256, 0, stream>>>(ei, rowst, cursor, srcs, dsts, E);

    const float* xcur = x;
    const int etiles = (E + 63) / 64;
    const int ntiles_node = (N + 63) / 64;
    for (int l = 0; l < L; l++) {
        node_kernel<<<768, 256, 0, stream>>>(xcur, B1T + (size_t)l * 16384, b1 + l * 128,
                                             PQ, C, N, ntiles_node);
        float* xo = (l & 1) ? x2 : x1;
        edge_kernel<<<768, 256, 0, stream>>>(PQ, C, srcs, dsts,
                                             W2T + (size_t)l * 16384, W3T + (size_t)l * 8192,
                                             w1c + l * 128, b2 + l * 128, b3 + l * 64,
                                             xo, E, etiles);
        xcur = xo;
    }
    pool_kernel<<<G, 256, 0, stream>>>(xcur, u, pooled, N, G);
    head_kernel<<<G, 64, 0, stream>>>(pooled, LW1, Lb1, LW2, Lb2, LW3, Lb3, (float*)d_out, G);
}

// Round 4
// 1750.175 us; speedup vs baseline: 1.2188x; 1.2037x over previous
//
#include <hip/hip_runtime.h>
#include <hip/hip_bf16.h>

typedef _Float16 f16;
typedef _Float16 f16x8 __attribute__((ext_vector_type(8)));
typedef float    f32x4 __attribute__((ext_vector_type(4)));
typedef float    f32x8 __attribute__((ext_vector_type(8)));

__device__ __forceinline__ float silu_f(float x) {
    // x * 1/(1+e^-x) via v_rcp_f32 (~1e-5 rel err, far below f16 rounding)
    return x * __builtin_amdgcn_rcpf(1.0f + __expf(-x));
}

// async 16B/lane global->LDS DMA (no result VGPRs -> compiler cannot serialize)
__device__ __forceinline__ void load_lds16(const f16* g, f16* l) {
    __builtin_amdgcn_global_load_lds(
        (const __attribute__((address_space(1))) void*)g,
        (__attribute__((address_space(3))) void*)l, 16, 0, 0);
}

// ---------------------------------------------------------------------------
// Weight prep: B1T[l][256][64] (node-GEMM B, P|Q columns), W2T[l][128][128],
// W3T[l][64][128] (transposed for MFMA B-fragments), w1c[l][128] f16 (dist2 row)
// ---------------------------------------------------------------------------
__global__ void prep_kernel(const float* __restrict__ W1, const float* __restrict__ W2,
                            const float* __restrict__ W3, f16* __restrict__ B1T,
                            f16* __restrict__ W2T, f16* __restrict__ W3T,
                            f16* __restrict__ w1c, int L, int total) {
    int idx = blockIdx.x * 256 + threadIdx.x;
    if (idx >= total) return;
    const int per = 16384 + 16384 + 8192 + 128;
    int l = idx / per, r = idx % per;
    const float* W1l = W1 + (size_t)l * 126 * 128;
    if (r < 16384) {                       // B1T: c in [0,256), k in [0,64)
        int c = r >> 6, k = r & 63;
        float v;
        if (c < 128) v = W1l[k * 128 + c];                       // P: xi @ W1[0:64]
        else v = (k >= 3) ? W1l[(64 + k - 3) * 128 + (c - 128)]  // Q: xj[3:] @ W1[64:125]
                          : 0.0f;
        B1T[(size_t)l * 16384 + r] = (f16)v;
    } else if (r < 32768) {                // W2T[n][k] = W2[k][n]
        int q = r - 16384, n = q >> 7, k = q & 127;
        W2T[(size_t)l * 16384 + q] = (f16)W2[(size_t)l * 16384 + k * 128 + n];
    } else if (r < 40960) {                // W3T[n][k] = W3[k][n]
        int q = r - 32768, n = q >> 7, k = q & 127;
        W3T[(size_t)l * 8192 + q] = (f16)W3[(size_t)l * 8192 + k * 64 + n];
    } else {                               // w1c = W1[125][:]
        int c = r - 40960;
        w1c[l * 128 + c] = (f16)W1l[125 * 128 + c];
    }
}

// ---------------------------------------------------------------------------
// CSR build: histogram over dst, 2-level exclusive scan, counting-sort scatter
// ---------------------------------------------------------------------------
__global__ void hist_kernel(const int* __restrict__ ei, int* __restrict__ deg, int E) {
    int i = blockIdx.x * 256 + threadIdx.x;
    if (i < E) atomicAdd(&deg[ei[E + i]], 1);
}

__global__ void scan_part(const int* __restrict__ deg, int* __restrict__ bsum, int N) {
    __shared__ int red[256];
    int t = threadIdx.x;
    int i = blockIdx.x * 256 + t;
    red[t] = (i < N) ? deg[i] : 0;
    __syncthreads();
    for (int s = 128; s > 0; s >>= 1) {
        if (t < s) red[t] += red[t + s];
        __syncthreads();
    }
    if (t == 0) bsum[blockIdx.x] = red[0];
}

__global__ void scan_mid(const int* __restrict__ bsum, int* __restrict__ boff, int nb) {
    __shared__ int sm[512];
    int t = threadIdx.x;
    int v = (t < nb) ? bsum[t] : 0;
    sm[t] = v;
    __syncthreads();
    for (int off = 1; off < 512; off <<= 1) {
        int a = (t >= off) ? sm[t - off] : 0;
        __syncthreads();
        sm[t] += a;
        __syncthreads();
    }
    if (t < nb) boff[t] = sm[t] - v;   // exclusive
}

__global__ void scan_final(const int* __restrict__ deg, const int* __restrict__ boff,
                           int* __restrict__ row_start, int N) {
    __shared__ int sm[256];
    int t = threadIdx.x;
    int i = blockIdx.x * 256 + t;
    int v = (i < N) ? deg[i] : 0;
    sm[t] = v;
    __syncthreads();
    for (int off = 1; off < 256; off <<= 1) {
        int a = (t >= off) ? sm[t - off] : 0;
        __syncthreads();
        sm[t] += a;
        __syncthreads();
    }
    if (i < N) row_start[i] = boff[blockIdx.x] + sm[t] - v;
}

__global__ void scatter_kernel(const int* __restrict__ ei, const int* __restrict__ row_start,
                               int* __restrict__ cursor, int* __restrict__ srcs,
                               int* __restrict__ dsts, int E) {
    int i = blockIdx.x * 256 + threadIdx.x;
    if (i < E) {
        int d = ei[E + i];
        int p = row_start[d] + atomicAdd(&cursor[d], 1);
        srcs[p] = ei[i];
        dsts[p] = d;
    }
}

// ---------------------------------------------------------------------------
// Node kernel: PQ[n][0:128] = x[n]@W1a + b1 ; PQ[n][128:256] = x[n,3:]@W1b
// Also emits C[n] = coords for dist2. MFMA 16x16x32 f16, 64-node tiles.
// ---------------------------------------------------------------------------
__global__ __launch_bounds__(256, 3) void node_kernel(
    const float* __restrict__ x, const f16* __restrict__ B1T,
    const float* __restrict__ b1, f16* __restrict__ PQ,
    float4* __restrict__ C, int N, int ntiles) {
    __shared__ f16 b1t[256 * 72];   // padded stride 72 (2-way bank aliasing only)
    const int tid = threadIdx.x;
    const int w = tid >> 6, lane = tid & 63, lm = lane & 15, kg = lane >> 4;

    for (int i = tid; i < 256 * 64; i += 256)
        b1t[(i >> 6) * 72 + (i & 63)] = B1T[i];
    __syncthreads();

    for (int tile = blockIdx.x; tile < ntiles; tile += gridDim.x) {
        const int base = tile * 64;
        int ar = base + w * 16 + lm;
        if (ar >= N) ar = N - 1;

        f16x8 afrag[2];
#pragma unroll
        for (int ks = 0; ks < 2; ks++) {
            f32x8 v = *(const f32x8*)(x + (size_t)ar * 64 + ks * 32 + kg * 8);
            f16x8 h;
#pragma unroll
            for (int j = 0; j < 8; j++) h[j] = (f16)v[j];
            afrag[ks] = h;
        }

        f32x4 acc[16];
#pragma unroll
        for (int nb = 0; nb < 16; nb++) acc[nb] = (f32x4){0.f, 0.f, 0.f, 0.f};
#pragma unroll
        for (int ks = 0; ks < 2; ks++)
#pragma unroll
            for (int nb = 0; nb < 16; nb++) {
                f16x8 b = *(const f16x8*)&b1t[(nb * 16 + lm) * 72 + ks * 32 + kg * 8];
                acc[nb] = __builtin_amdgcn_mfma_f32_16x16x32_f16(afrag[ks], b, acc[nb], 0, 0, 0);
            }

#pragma unroll
        for (int nb = 0; nb < 16; nb++) {
            int col = nb * 16 + lm;
            float bias = (col < 128) ? b1[col] : 0.0f;
#pragma unroll
            for (int reg = 0; reg < 4; reg++) {
                int orow = base + w * 16 + kg * 4 + reg;
                if (orow < N) PQ[(size_t)orow * 256 + col] = (f16)(acc[nb][reg] + bias);
            }
        }
        if (tid < 64) {
            int n = base + tid;
            if (n < N) {
                const float* xr = x + (size_t)n * 64;
                C[n] = make_float4(xr[0], xr[1], xr[2], 0.0f);
            }
        }
    }
}

// ---------------------------------------------------------------------------
// Edge kernel v4: async-staged gathers via global_load_lds (batched MLP).
// Per wave, per tile: 8 x 16B/lane DMA gathers (p|q of its 16 edges) -> LDS,
// ONE s_waitcnt vmcnt(0), then conflict-free ds_read_b128 A-fragments.
// Staging for tile n+1 issues right after GEMM1 of tile n (stage dead then),
// hiding gather latency behind GEMM2 + scan. LDS 78.6KB -> 2 blocks/CU.
// ---------------------------------------------------------------------------
__global__ __launch_bounds__(256, 2) void edge_kernel(
    const f16* __restrict__ PQ, const float4* __restrict__ C,
    const int* __restrict__ srcs, const int* __restrict__ dsts,
    const f16* __restrict__ W2T, const f16* __restrict__ W3T,
    const f16* __restrict__ w1c, const float* __restrict__ b2,
    const float* __restrict__ b3, float* __restrict__ xout,
    int E, int ntiles) {
    __shared__ f16 w2t[128 * 128];     // 32KB, XOR-swizzled
    __shared__ f16 stage[4 * 4096];    // 32KB: per-wave p(2048 f16)|q(2048 f16)
    __shared__ f16 tb[4 * 16 * 36];    // 4.5KB: per-wave h2-transpose slices
    __shared__ f16 mreg[64 * 66];      // 8.25KB: m tile (padded stride 66)

    const int tid = threadIdx.x;
    const int w = tid >> 6, lane = tid & 63, lm = lane & 15, kg = lane >> 4;
    const int e4 = lane >> 2, c4 = lane & 3;   // staging: lane = e4*4 + c4

    for (int i = tid; i < 128 * 128; i += 256) {
        int n = i >> 7, k = i & 127;
        w2t[n * 128 + (((k >> 3) ^ (n & 15)) << 3) + (k & 7)] = W2T[i];
    }

    // loop-invariant hoists
    f16x8 wvh[4];
#pragma unroll
    for (int ks = 0; ks < 4; ks++) wvh[ks] = *(const f16x8*)(w1c + ks * 32 + kg * 8);
    float bias2[8], bias3[4];
#pragma unroll
    for (int nb = 0; nb < 8; nb++) bias2[nb] = b2[nb * 16 + lm];
#pragma unroll
    for (int nb = 0; nb < 4; nb++) bias3[nb] = b3[nb * 16 + lm];
    __syncthreads();

    f16* sw = stage + w * 4096;        // this wave's stage: p at 0, q at 2048
    f16* tbuf = tb + w * (16 * 36);
    const int gstride = gridDim.x;

    // ---- prologue: tile-0 indices, C, async staging ----
    int tile = blockIdx.x;
    int er = tile * 64 + w * 16 + lm;
    if (er >= E) er = E - 1;
    int s = srcs[er], d = dsts[er];
    float4 cs = C[s], cd = C[d];
    {
        int de = __shfl(d, e4), se = __shfl(s, e4);
        const f16* gp = PQ + (size_t)de * 256 + c4 * 8;
        const f16* gq = PQ + (size_t)se * 256 + 128 + c4 * 8;
#pragma unroll
        for (int j = 0; j < 4; j++) load_lds16(gp + j * 32, sw + j * 512 + lane * 8);
#pragma unroll
        for (int j = 0; j < 4; j++) load_lds16(gq + j * 32, sw + 2048 + j * 512 + lane * 8);
    }

    while (tile < ntiles) {
        const int base = tile * 64;
        const int rows = min(64, E - base);
        const int ntile = tile + gstride;

        float dx = cs.x - cd.x, dy = cs.y - cd.y, dz = cs.z - cd.z;
        float dist2 = dx * dx + dy * dy + dz * dz;

        // ---- ONE wait for all staged DMA + prefetched C/idx, then LDS reads ----
        asm volatile("s_waitcnt vmcnt(0)" ::: "memory");
        f16x8 afrag[4];
#pragma unroll
        for (int ks = 0; ks < 4; ks++) {
            f16x8 p = *(const f16x8*)&sw[ks * 512 + lm * 32 + kg * 8];
            f16x8 q = *(const f16x8*)&sw[2048 + ks * 512 + lm * 32 + kg * 8];
            f16x8 h;
#pragma unroll
            for (int j = 0; j < 8; j++) {
                float v = (float)p[j] + (float)q[j] + dist2 * (float)wvh[ks][j];
                h[j] = (f16)silu_f(v);
            }
            afrag[ks] = h;
        }

        // ---- GEMM1: h1 @ W2 ----
        f32x4 acc1[8];
#pragma unroll
        for (int nb = 0; nb < 8; nb++) acc1[nb] = (f32x4){0.f, 0.f, 0.f, 0.f};
#pragma unroll
        for (int ks = 0; ks < 4; ks++)
#pragma unroll
            for (int nb = 0; nb < 8; nb++) {
                int n = nb * 16 + lm;
                f16x8 b = *(const f16x8*)&w2t[n * 128 + (((ks * 4 + kg) ^ (n & 15)) << 3)];
                acc1[nb] = __builtin_amdgcn_mfma_f32_16x16x32_f16(afrag[ks], b, acc1[nb], 0, 0, 0);
            }

        // ---- stage buffer is dead now: prefetch next tile (idx, C, DMA) ----
        int er2 = ntile * 64 + w * 16 + lm;
        if (ntile >= ntiles) er2 = er;
        if (er2 >= E) er2 = E - 1;
        const int s2 = srcs[er2], d2 = dsts[er2];
        const float4 cs2 = C[s2], cd2 = C[d2];
        if (ntile < ntiles) {
            int de = __shfl(d2, e4), se = __shfl(s2, e4);
            const f16* gp = PQ + (size_t)de * 256 + c4 * 8;
            const f16* gq = PQ + (size_t)se * 256 + 128 + c4 * 8;
#pragma unroll
            for (int j = 0; j < 4; j++) load_lds16(gp + j * 32, sw + j * 512 + lane * 8);
#pragma unroll
            for (int j = 0; j < 4; j++) load_lds16(gq + j * 32, sw + 2048 + j * 512 + lane * 8);
        }

        // ---- GEMM2 in 4 k-quarters via wave-private tbuf ----
        f32x4 acc2[4];
#pragma unroll
        for (int nb2 = 0; nb2 < 4; nb2++) acc2[nb2] = (f32x4){0.f, 0.f, 0.f, 0.f};
#pragma unroll
        for (int kq = 0; kq < 4; kq++) {
#pragma unroll
            for (int nn = 0; nn < 2; nn++) {
                int nb = kq * 2 + nn;
#pragma unroll
                for (int reg = 0; reg < 4; reg++)
                    tbuf[(kg * 4 + reg) * 36 + nn * 16 + lm] =
                        (f16)silu_f(acc1[nb][reg] + bias2[nb]);
            }
            f16x8 a2 = *(const f16x8*)&tbuf[lm * 36 + kg * 8];
#pragma unroll
            for (int nb2 = 0; nb2 < 4; nb2++) {
                f16x8 b = *(const f16x8*)(W3T + (size_t)(nb2 * 16 + lm) * 128 +
                                          kq * 32 + kg * 8);
                acc2[nb2] = __builtin_amdgcn_mfma_f32_16x16x32_f16(a2, b, acc2[nb2], 0, 0, 0);
            }
        }

        // ---- m = silu(acc2+b3) -> f16 LDS region ----
#pragma unroll
        for (int nb2 = 0; nb2 < 4; nb2++) {
            int c = nb2 * 16 + lm;
            float bias = bias3[nb2];
#pragma unroll
            for (int reg = 0; reg < 4; reg++) {
                int r = w * 16 + kg * 4 + reg;
                mreg[r * 66 + c] = (f16)silu_f(acc2[nb2][reg] + bias);
            }
        }
        __syncthreads();

        // ---- tile-wide segmented scan over sorted dst (dsts[] L1-hot) ----
        {
            const int ch = tid & 63;
            const int rg = tid >> 6;
            for (int it = 0; it < 16; it++) {
                int r = it * 4 + rg;
                if (r < rows) {
                    int dr = dsts[base + r];
                    bool head = (r == 0) || (dsts[base + r - 1] != dr);
                    if (head) {
                        float sum = (float)mreg[r * 66 + ch];
                        int rr = r + 1;
                        while (rr < rows && dsts[base + rr] == dr) {
                            sum += (float)mreg[rr * 66 + ch];
                            rr++;
                        }
                        float* p = xout + (size_t)dr * 64 + ch;
                        if (r == 0 || rr == rows) atomicAdd(p, sum);  // may span tiles
                        else *p = sum;                                 // exclusive owner
                    }
                }
            }
        }
        __syncthreads();   // scan reads done before next tile overwrites mreg

        // ---- rotate pipeline state ----
        tile = ntile;
        er = er2; s = s2; d = d2;
        cs = cs2; cd = cd2;
    }
    asm volatile("s_waitcnt vmcnt(0)" ::: "memory");  // drain any stray DMA
}

// ---------------------------------------------------------------------------
// Pooling: per-graph add/mean/max over contiguous node ranges (batch = n*G//N)
// ---------------------------------------------------------------------------
__global__ void pool_kernel(const float* __restrict__ xf, const float* __restrict__ u,
                            float* __restrict__ pooled, int N, int G) {
    int g = blockIdx.x;
    int t = threadIdx.x;
    int ch = t & 63, sub = t >> 6;
    long long n0 = ((long long)g * N + G - 1) / G;
    long long n1 = ((long long)(g + 1) * N + G - 1) / G;
    float sm = 0.f, mx = -3.0e38f;
    for (long long n = n0 + sub; n < n1; n += 4) {
        float v = xf[n * 64 + ch];
        sm += v;
        mx = fmaxf(mx, v);
    }
    __shared__ float ssum[256], smax[256];
    ssum[t] = sm;
    smax[t] = mx;
    __syncthreads();
    if (sub == 0) {
        float a = ssum[ch] + ssum[64 + ch] + ssum[128 + ch] + ssum[192 + ch];
        float m = fmaxf(fmaxf(smax[ch], smax[64 + ch]), fmaxf(smax[128 + ch], smax[192 + ch]));
        float cnt = (float)(n1 - n0);
        pooled[g * 194 + ch] = a;
        pooled[g * 194 + 64 + ch] = a / fmaxf(cnt, 1.f);
        pooled[g * 194 + 128 + ch] = m;
    }
    if (t == 0) {
        pooled[g * 194 + 192] = u[g * 2];
        pooled[g * 194 + 193] = u[g * 2 + 1];
    }
}

// ---------------------------------------------------------------------------
// Readout head (fp32): [G,194]@[194,64] silu, @[64,64] silu, @[64,2]
// ---------------------------------------------------------------------------
__global__ void head_kernel(const float* __restrict__ pooled,
                            const float* __restrict__ LW1, const float* __restrict__ Lb1,
                            const float* __restrict__ LW2, const float* __restrict__ Lb2,
                            const float* __restrict__ LW3, const float* __restrict__ Lb3,
                            float* __restrict__ out, int G) {
    int g = blockIdx.x, t = threadIdx.x;
    __shared__ float pl[194];
    __shared__ float hl[64];
    for (int k = t; k < 194; k += 64) pl[k] = pooled[g * 194 + k];
    __syncthreads();
    float a = Lb1[t];
    for (int k = 0; k < 194; k++) a += pl[k] * LW1[k * 64 + t];
    a = a / (1.0f + __expf(-a));
    hl[t] = a;
    __syncthreads();
    float b = Lb2[t];
    for (int k = 0; k < 64; k++) b += hl[k] * LW2[k * 64 + t];
    b = b / (1.0f + __expf(-b));
    __syncthreads();
    hl[t] = b;
    __syncthreads();
    if (t < 2) {
        float c = Lb3[t];
        for (int k = 0; k < 64; k++) c += hl[k] * LW3[k * 2 + t];
        out[g * 2 + t] = c;
    }
}

// ---------------------------------------------------------------------------
extern "C" void kernel_launch(void* const* d_in, const int* in_sizes, int n_in,
                              void* d_out, int out_size, void* d_ws, size_t ws_size,
                              hipStream_t stream) {
    const float* x   = (const float*)d_in[0];
    const float* u   = (const float*)d_in[1];
    const int*   ei  = (const int*)d_in[2];
    const float* W1  = (const float*)d_in[4];
    const float* b1  = (const float*)d_in[5];
    const float* W2  = (const float*)d_in[6];
    const float* b2  = (const float*)d_in[7];
    const float* W3  = (const float*)d_in[8];
    const float* b3  = (const float*)d_in[9];
    const float* LW1 = (const float*)d_in[10];
    const float* Lb1 = (const float*)d_in[11];
    const float* LW2 = (const float*)d_in[12];
    const float* Lb2 = (const float*)d_in[13];
    const float* LW3 = (const float*)d_in[14];
    const float* Lb3 = (const float*)d_in[15];

    const int N = in_sizes[0] / 64;
    const int G = in_sizes[1] / 2;
    const int E = in_sizes[2] / 2;
    const int L = in_sizes[4] / (126 * 128);

    char* ws = (char*)d_ws;
    size_t off = 0;
    auto alloc = [&](size_t bytes) -> char* {
        char* p = ws + off;
        off += (bytes + 511) & ~(size_t)511;
        return p;
    };
    f16*    PQ     = (f16*)alloc((size_t)N * 256 * 2);
    float4* C      = (float4*)alloc((size_t)N * 16);
    float*  x1     = (float*)alloc((size_t)N * 64 * 4);
    float*  x2     = (float*)alloc((size_t)N * 64 * 4);
    int*    srcs   = (int*)alloc((size_t)E * 4);
    int*    dsts   = (int*)alloc((size_t)E * 4);
    int*    deg    = (int*)alloc((size_t)N * 4);
    int*    rowst  = (int*)alloc((size_t)N * 4);
    int*    cursor = (int*)alloc((size_t)N * 4);
    int*    bsum   = (int*)alloc(4096);
    int*    boff   = (int*)alloc(4096);
    f16*    B1T    = (f16*)alloc((size_t)L * 256 * 64 * 2);
    f16*    W2T    = (f16*)alloc((size_t)L * 128 * 128 * 2);
    f16*    W3T    = (f16*)alloc((size_t)L * 64 * 128 * 2);
    f16*    w1c    = (f16*)alloc((size_t)L * 128 * 2);
    float*  pooled = (float*)alloc((size_t)G * 194 * 4);
    (void)ws_size;
    (void)n_in;
    (void)out_size;

    hipMemsetAsync(deg, 0, (size_t)N * 4, stream);
    hipMemsetAsync(cursor, 0, (size_t)N * 4, stream);
    hipMemsetAsync(x1, 0, (size_t)N * 64 * 4, stream);
    hipMemsetAsync(x2, 0, (size_t)N * 64 * 4, stream);

    {
        int total = L * (16384 + 16384 + 8192 + 128);
        prep_kernel<<<(total + 255) / 256, 256, 0, stream>>>(W1, W2, W3, B1T, W2T, W3T, w1c, L, total);
    }
    hist_kernel<<<(E + 255) / 256, 256, 0, stream>>>(ei, deg, E);
    int NB = (N + 255) / 256;
    scan_part<<<NB, 256, 0, stream>>>(deg, bsum, N);
    scan_mid<<<1, 512, 0, stream>>>(bsum, boff, NB);
    scan_final<<<NB, 256, 0, stream>>>(deg, boff, rowst, N);
    scatter_kernel<<<(E + 255) / 256, 256, 0, stream>>>(ei, rowst, cursor, srcs, dsts, E);

    const float* xcur = x;
    const int etiles = (E + 63) / 64;
    const int ntiles_node = (N + 63) / 64;
    for (int l = 0; l < L; l++) {
        node_kernel<<<768, 256, 0, stream>>>(xcur, B1T + (size_t)l * 16384, b1 + l * 128,
                                             PQ, C, N, ntiles_node);
        float* xo = (l & 1) ? x2 : x1;
        edge_kernel<<<512, 256, 0, stream>>>(PQ, C, srcs, dsts,
                                             W2T + (size_t)l * 16384, W3T + (size_t)l * 8192,
                                             w1c + l * 128, b2 + l * 128, b3 + l * 64,
                                             xo, E, etiles);
        xcur = xo;
    }
    pool_kernel<<<G, 256, 0, stream>>>(xcur, u, pooled, N, G);
    head_kernel<<<G, 64, 0, stream>>>(pooled, LW1, Lb1, LW2, Lb2, LW3, Lb3, (float*)d_out, G);
}

// Round 5
// 1024.114 us; speedup vs baseline: 2.0830x; 1.7090x over previous
//
#include <hip/hip_runtime.h>
#include <hip/hip_bf16.h>

typedef _Float16 f16;
typedef _Float16 f16x8 __attribute__((ext_vector_type(8)));
typedef float    f32x4 __attribute__((ext_vector_type(4)));
typedef float    f32x8 __attribute__((ext_vector_type(8)));

__device__ __forceinline__ float silu_f(float x) {
    // x * 1/(1+e^-x) via v_rcp_f32 (~1e-5 rel err, far below f16 rounding)
    return x * __builtin_amdgcn_rcpf(1.0f + __expf(-x));
}

// async 16B/lane global->LDS DMA: HW semantics = wave-uniform LDS base + lane*16
__device__ __forceinline__ void load_lds16(const f16* g, f16* l) {
    __builtin_amdgcn_global_load_lds(
        (const __attribute__((address_space(1))) void*)g,
        (__attribute__((address_space(3))) void*)l, 16, 0, 0);
}

// ---------------------------------------------------------------------------
// Weight prep: B1T[l][256][64] (node-GEMM B, P|Q columns), W2T[l][128][128],
// W3T[l][64][128] (transposed for MFMA B-fragments), w1c[l][128] f16 (dist2 row)
// ---------------------------------------------------------------------------
__global__ void prep_kernel(const float* __restrict__ W1, const float* __restrict__ W2,
                            const float* __restrict__ W3, f16* __restrict__ B1T,
                            f16* __restrict__ W2T, f16* __restrict__ W3T,
                            f16* __restrict__ w1c, int L, int total) {
    int idx = blockIdx.x * 256 + threadIdx.x;
    if (idx >= total) return;
    const int per = 16384 + 16384 + 8192 + 128;
    int l = idx / per, r = idx % per;
    const float* W1l = W1 + (size_t)l * 126 * 128;
    if (r < 16384) {                       // B1T: c in [0,256), k in [0,64)
        int c = r >> 6, k = r & 63;
        float v;
        if (c < 128) v = W1l[k * 128 + c];                       // P: xi @ W1[0:64]
        else v = (k >= 3) ? W1l[(64 + k - 3) * 128 + (c - 128)]  // Q: xj[3:] @ W1[64:125]
                          : 0.0f;
        B1T[(size_t)l * 16384 + r] = (f16)v;
    } else if (r < 32768) {                // W2T[n][k] = W2[k][n]
        int q = r - 16384, n = q >> 7, k = q & 127;
        W2T[(size_t)l * 16384 + q] = (f16)W2[(size_t)l * 16384 + k * 128 + n];
    } else if (r < 40960) {                // W3T[n][k] = W3[k][n]
        int q = r - 32768, n = q >> 7, k = q & 127;
        W3T[(size_t)l * 8192 + q] = (f16)W3[(size_t)l * 8192 + k * 64 + n];
    } else {                               // w1c = W1[125][:]
        int c = r - 40960;
        w1c[l * 128 + c] = (f16)W1l[125 * 128 + c];
    }
}

// ---------------------------------------------------------------------------
// CSR build: histogram over dst, 2-level exclusive scan, counting-sort scatter
// ---------------------------------------------------------------------------
__global__ void hist_kernel(const int* __restrict__ ei, int* __restrict__ deg, int E) {
    int i = blockIdx.x * 256 + threadIdx.x;
    if (i < E) atomicAdd(&deg[ei[E + i]], 1);
}

__global__ void scan_part(const int* __restrict__ deg, int* __restrict__ bsum, int N) {
    __shared__ int red[256];
    int t = threadIdx.x;
    int i = blockIdx.x * 256 + t;
    red[t] = (i < N) ? deg[i] : 0;
    __syncthreads();
    for (int s = 128; s > 0; s >>= 1) {
        if (t < s) red[t] += red[t + s];
        __syncthreads();
    }
    if (t == 0) bsum[blockIdx.x] = red[0];
}

__global__ void scan_mid(const int* __restrict__ bsum, int* __restrict__ boff, int nb) {
    __shared__ int sm[512];
    int t = threadIdx.x;
    int v = (t < nb) ? bsum[t] : 0;
    sm[t] = v;
    __syncthreads();
    for (int off = 1; off < 512; off <<= 1) {
        int a = (t >= off) ? sm[t - off] : 0;
        __syncthreads();
        sm[t] += a;
        __syncthreads();
    }
    if (t < nb) boff[t] = sm[t] - v;   // exclusive
}

__global__ void scan_final(const int* __restrict__ deg, const int* __restrict__ boff,
                           int* __restrict__ row_start, int N) {
    __shared__ int sm[256];
    int t = threadIdx.x;
    int i = blockIdx.x * 256 + t;
    int v = (i < N) ? deg[i] : 0;
    sm[t] = v;
    __syncthreads();
    for (int off = 1; off < 256; off <<= 1) {
        int a = (t >= off) ? sm[t - off] : 0;
        __syncthreads();
        sm[t] += a;
        __syncthreads();
    }
    if (i < N) row_start[i] = boff[blockIdx.x] + sm[t] - v;
}

__global__ void scatter_kernel(const int* __restrict__ ei, const int* __restrict__ row_start,
                               int* __restrict__ cursor, int* __restrict__ srcs,
                               int* __restrict__ dsts, int E) {
    int i = blockIdx.x * 256 + threadIdx.x;
    if (i < E) {
        int d = ei[E + i];
        int p = row_start[d] + atomicAdd(&cursor[d], 1);
        srcs[p] = ei[i];
        dsts[p] = d;
    }
}

// ---------------------------------------------------------------------------
// Node kernel: PQ[n][0:128] = x[n]@W1a + b1 ; PQ[n][128:256] = x[n,3:]@W1b
// Also emits C[n] = coords for dist2. MFMA 16x16x32 f16, 64-node tiles.
// ---------------------------------------------------------------------------
__global__ __launch_bounds__(256, 3) void node_kernel(
    const float* __restrict__ x, const f16* __restrict__ B1T,
    const float* __restrict__ b1, f16* __restrict__ PQ,
    float4* __restrict__ C, int N, int ntiles) {
    __shared__ f16 b1t[256 * 72];   // padded stride 72 (2-way bank aliasing only)
    const int tid = threadIdx.x;
    const int w = tid >> 6, lane = tid & 63, lm = lane & 15, kg = lane >> 4;

    for (int i = tid; i < 256 * 64; i += 256)
        b1t[(i >> 6) * 72 + (i & 63)] = B1T[i];
    __syncthreads();

    for (int tile = blockIdx.x; tile < ntiles; tile += gridDim.x) {
        const int base = tile * 64;
        int ar = base + w * 16 + lm;
        if (ar >= N) ar = N - 1;

        f16x8 afrag[2];
#pragma unroll
        for (int ks = 0; ks < 2; ks++) {
            f32x8 v = *(const f32x8*)(x + (size_t)ar * 64 + ks * 32 + kg * 8);
            f16x8 h;
#pragma unroll
            for (int j = 0; j < 8; j++) h[j] = (f16)v[j];
            afrag[ks] = h;
        }

        f32x4 acc[16];
#pragma unroll
        for (int nb = 0; nb < 16; nb++) acc[nb] = (f32x4){0.f, 0.f, 0.f, 0.f};
#pragma unroll
        for (int ks = 0; ks < 2; ks++)
#pragma unroll
            for (int nb = 0; nb < 16; nb++) {
                f16x8 b = *(const f16x8*)&b1t[(nb * 16 + lm) * 72 + ks * 32 + kg * 8];
                acc[nb] = __builtin_amdgcn_mfma_f32_16x16x32_f16(afrag[ks], b, acc[nb], 0, 0, 0);
            }

#pragma unroll
        for (int nb = 0; nb < 16; nb++) {
            int col = nb * 16 + lm;
            float bias = (col < 128) ? b1[col] : 0.0f;
#pragma unroll
            for (int reg = 0; reg < 4; reg++) {
                int orow = base + w * 16 + kg * 4 + reg;
                if (orow < N) PQ[(size_t)orow * 256 + col] = (f16)(acc[nb][reg] + bias);
            }
        }
        if (tid < 64) {
            int n = base + tid;
            if (n < N) {
                const float* xr = x + (size_t)n * 64;
                C[n] = make_float4(xr[0], xr[1], xr[2], 0.0f);
            }
        }
    }
}

// ---------------------------------------------------------------------------
// Edge kernel v5: fully wave-independent 16-edge tiles, barrier-free.
//   stage: async global_load_lds gathers (16B/lane), hand-counted vmcnt(2)
//   h1 -> GEMM1 (w2t LDS) -> GEMM2 (double-buffered quarter transpose)
//   segmented reduce done ENTIRELY in registers via shfl mask arithmetic
//   (zero dependent memory loads), unconditional atomics (~51MB/layer).
// LDS 32 (w2t) + 32 (stage) + 9 (tb x2) = 73KB -> 2 blocks/CU, 8 free waves.
// ---------------------------------------------------------------------------
__global__ __launch_bounds__(256, 2) void edge_kernel(
    const f16* __restrict__ PQ, const float4* __restrict__ C,
    const int* __restrict__ srcs, const int* __restrict__ dsts,
    const f16* __restrict__ W2T, const f16* __restrict__ W3T,
    const f16* __restrict__ w1c, const float* __restrict__ b2,
    const float* __restrict__ b3, float* __restrict__ xout,
    int E, int wtiles) {
    __shared__ f16 w2t[128 * 128];       // 32KB, XOR-swizzled
    __shared__ f16 stage[4 * 4096];      // 32KB: per-wave p(2048)|q(2048)
    __shared__ f16 tb[2 * 4 * 576];      // 9KB: double-buffered quarter slices

    const int tid = threadIdx.x;
    const int w = tid >> 6, lane = tid & 63, lm = lane & 15, kg = lane >> 4;
    const int e4 = lane >> 2, c4 = lane & 3;   // staging: lane = e4*4 + c4

    for (int i = tid; i < 128 * 128; i += 256) {
        int n = i >> 7, k = i & 127;
        w2t[n * 128 + (((k >> 3) ^ (n & 15)) << 3) + (k & 7)] = W2T[i];
    }

    // loop-invariant hoists
    f16x8 wvh[4];
#pragma unroll
    for (int ks = 0; ks < 4; ks++) wvh[ks] = *(const f16x8*)(w1c + ks * 32 + kg * 8);
    float bias2[8], bias3[4];
#pragma unroll
    for (int nb = 0; nb < 8; nb++) bias2[nb] = b2[nb * 16 + lm];
#pragma unroll
    for (int nb = 0; nb < 4; nb++) bias3[nb] = b3[nb * 16 + lm];
    __syncthreads();   // w2t ready; no barriers after this point

    f16* sw = stage + w * 4096;          // wave stage: p at 0, q at 2048
    const int nwaves = gridDim.x * 4;

    // ---- prologue: tile-0 state + async staging ----
    int t = blockIdx.x * 4 + w;
    int e0 = t * 16 + lm;
    int erc = min(e0, E - 1);
    int scl = srcs[erc];
    int dcl = dsts[erc];
    int dsen = (e0 < E) ? dcl : -1;
    float4 cs = C[scl], cd = C[dcl];
    {
        int de = __shfl(dcl, e4), se = __shfl(scl, e4);
        const f16* gp = PQ + (size_t)de * 256 + c4 * 8;
        const f16* gq = PQ + (size_t)se * 256 + 128 + c4 * 8;
#pragma unroll
        for (int j = 0; j < 4; j++) load_lds16(gp + j * 32, sw + j * 512 + lane * 8);
#pragma unroll
        for (int j = 0; j < 4; j++) load_lds16(gq + j * 32, sw + 2048 + j * 512 + lane * 8);
    }

    while (t < wtiles) {
        const int tn = t + nwaves;

        // ---- issue next-tile idx loads, then wait stage leaving exactly them ----
        int e1 = tn * 16 + lm;
        int erc2 = min(e1, E - 1);
        int s2c = srcs[erc2];
        int d2c = dsts[erc2];
        asm volatile("s_waitcnt vmcnt(2)" ::: "memory");   // stage DMA drained

        float dx = cs.x - cd.x, dy = cs.y - cd.y, dz = cs.z - cd.z;
        float dist2 = dx * dx + dy * dy + dz * dz;

        // ---- h1 from stage -> A fragments ----
        f16x8 afrag[4];
#pragma unroll
        for (int ks = 0; ks < 4; ks++) {
            f16x8 p = *(const f16x8*)&sw[ks * 512 + lm * 32 + kg * 8];
            f16x8 q = *(const f16x8*)&sw[2048 + ks * 512 + lm * 32 + kg * 8];
            f16x8 h;
#pragma unroll
            for (int j = 0; j < 8; j++) {
                float v = (float)p[j] + (float)q[j] + dist2 * (float)wvh[ks][j];
                h[j] = (f16)silu_f(v);
            }
            afrag[ks] = h;
        }

        // ---- GEMM1: h1 @ W2 ----
        f32x4 acc1[8];
#pragma unroll
        for (int nb = 0; nb < 8; nb++) acc1[nb] = (f32x4){0.f, 0.f, 0.f, 0.f};
#pragma unroll
        for (int ks = 0; ks < 4; ks++)
#pragma unroll
            for (int nb = 0; nb < 8; nb++) {
                int n = nb * 16 + lm;
                f16x8 b = *(const f16x8*)&w2t[n * 128 + (((ks * 4 + kg) ^ (n & 15)) << 3)];
                acc1[nb] = __builtin_amdgcn_mfma_f32_16x16x32_f16(afrag[ks], b, acc1[nb], 0, 0, 0);
            }

        // ---- stage dead: prefetch next tile (C + DMA) ----
        const int d2sen = (e1 < E) ? d2c : -1;
        const float4 cs2 = C[s2c], cd2 = C[d2c];
        asm volatile("" ::: "memory");   // keep DMA after stage reads
        if (tn < wtiles) {
            int de = __shfl(d2c, e4), se = __shfl(s2c, e4);
            const f16* gp = PQ + (size_t)de * 256 + c4 * 8;
            const f16* gq = PQ + (size_t)se * 256 + 128 + c4 * 8;
#pragma unroll
            for (int j = 0; j < 4; j++) load_lds16(gp + j * 32, sw + j * 512 + lane * 8);
#pragma unroll
            for (int j = 0; j < 4; j++) load_lds16(gq + j * 32, sw + 2048 + j * 512 + lane * 8);
        }

        // ---- GEMM2 in 4 k-quarters via double-buffered wave slices ----
        f32x4 acc2[4];
#pragma unroll
        for (int nb2 = 0; nb2 < 4; nb2++) acc2[nb2] = (f32x4){0.f, 0.f, 0.f, 0.f};
#pragma unroll
        for (int kq = 0; kq < 4; kq++) {
            f16* tq = tb + (kq & 1) * (4 * 576) + w * 576;
#pragma unroll
            for (int nn = 0; nn < 2; nn++) {
                int nb = kq * 2 + nn;
#pragma unroll
                for (int reg = 0; reg < 4; reg++)
                    tq[(kg * 4 + reg) * 36 + nn * 16 + lm] =
                        (f16)silu_f(acc1[nb][reg] + bias2[nb]);
            }
            f16x8 a2 = *(const f16x8*)&tq[lm * 36 + kg * 8];
#pragma unroll
            for (int nb2 = 0; nb2 < 4; nb2++) {
                f16x8 b = *(const f16x8*)(W3T + (size_t)(nb2 * 16 + lm) * 128 +
                                          kq * 32 + kg * 8);
                acc2[nb2] = __builtin_amdgcn_mfma_f32_16x16x32_f16(a2, b, acc2[nb2], 0, 0, 0);
            }
        }

        // ---- in-register segmented reduce over this wave's 16 sorted rows ----
        {
            // dst ids of my 4 owned rows (row = kg*4+reg), via shfl (VALU only)
            const int r0 = kg * 4;
            const int dr0 = __shfl(dsen, r0);
            const int dr1 = __shfl(dsen, r0 + 1);
            const int dr2 = __shfl(dsen, r0 + 2);
            const int dr3 = __shfl(dsen, r0 + 3);
            int prevv = __shfl(dsen, (r0 - 1) & 63);
            if (kg == 0) prevv = -1234567;        // wave-tile boundary

            const bool e01 = dr0 == dr1, e12 = dr1 == dr2, e23 = dr2 == dr3;
            const bool c01 = e01, c02 = e01 && e12, c03 = c02 && e23;
            const bool c12 = e12, c13 = e12 && e23;
            const int fullI = c03 ? 1 : 0;

            // cross-kg continuation masks for the run containing my row 3
            const int tgt = dr3;
            const int l1i = (lane + 16) & 63, l2i = (lane + 32) & 63, l3i = (lane + 48) & 63;
            const int dr0_1 = __shfl(dr0, l1i), fu1 = __shfl(fullI, l1i);
            const int dr0_2 = __shfl(dr0, l2i), fu2 = __shfl(fullI, l2i);
            const int dr0_3 = __shfl(dr0, l3i);
            const bool take1 = (kg <= 2) && (dr0_1 == tgt);
            const bool take2 = take1 && fu1 && (kg <= 1) && (dr0_2 == tgt);
            const bool take3 = take2 && fu2 && (kg == 0) && (dr0_3 == tgt);

            const bool h0 = (dr0 != prevv) && (dr0 >= 0);
            const bool h1f = (!e01) && (dr1 >= 0);
            const bool h2f = (!e12) && (dr2 >= 0);
            const bool h3f = (!e23) && (dr3 >= 0);

            float t0v[4], t1v[4], t2v[4], t3v[4];
#pragma unroll
            for (int nb2 = 0; nb2 < 4; nb2++) {
                const float bias = bias3[nb2];
                const float v0 = silu_f(acc2[nb2][0] + bias);
                const float v1 = silu_f(acc2[nb2][1] + bias);
                const float v2 = silu_f(acc2[nb2][2] + bias);
                const float v3 = silu_f(acc2[nb2][3] + bias);
                float lead = v0 + (c01 ? v1 : 0.f) + (c02 ? v2 : 0.f) + (c03 ? v3 : 0.f);
                float ext = 0.f;
                const float le1 = __shfl(lead, l1i);
                const float le2 = __shfl(lead, l2i);
                const float le3 = __shfl(lead, l3i);
                if (take1) ext += le1;
                if (take2) ext += le2;
                if (take3) ext += le3;
                t0v[nb2] = lead + (c03 ? ext : 0.f);
                t1v[nb2] = v1 + (c12 ? v2 : 0.f) + (c13 ? (v3 + ext) : 0.f);
                t2v[nb2] = v2 + (e23 ? (v3 + ext) : 0.f);
                t3v[nb2] = v3 + ext;
            }
            if (h0) {
                float* p = xout + (size_t)dr0 * 64 + lm;
#pragma unroll
                for (int nb2 = 0; nb2 < 4; nb2++) atomicAdd(p + nb2 * 16, t0v[nb2]);
            }
            if (h1f) {
                float* p = xout + (size_t)dr1 * 64 + lm;
#pragma unroll
                for (int nb2 = 0; nb2 < 4; nb2++) atomicAdd(p + nb2 * 16, t1v[nb2]);
            }
            if (h2f) {
                float* p = xout + (size_t)dr2 * 64 + lm;
#pragma unroll
                for (int nb2 = 0; nb2 < 4; nb2++) atomicAdd(p + nb2 * 16, t2v[nb2]);
            }
            if (h3f) {
                float* p = xout + (size_t)dr3 * 64 + lm;
#pragma unroll
                for (int nb2 = 0; nb2 < 4; nb2++) atomicAdd(p + nb2 * 16, t3v[nb2]);
            }
        }

        // ---- rotate pipeline state ----
        t = tn;
        scl = s2c; dcl = d2c; dsen = d2sen;
        cs = cs2; cd = cd2;
    }
    asm volatile("s_waitcnt vmcnt(0)" ::: "memory");  // drain any stray DMA
}

// ---------------------------------------------------------------------------
// Pooling: per-graph add/mean/max over contiguous node ranges (batch = n*G//N)
// ---------------------------------------------------------------------------
__global__ void pool_kernel(const float* __restrict__ xf, const float* __restrict__ u,
                            float* __restrict__ pooled, int N, int G) {
    int g = blockIdx.x;
    int t = threadIdx.x;
    int ch = t & 63, sub = t >> 6;
    long long n0 = ((long long)g * N + G - 1) / G;
    long long n1 = ((long long)(g + 1) * N + G - 1) / G;
    float sm = 0.f, mx = -3.0e38f;
    for (long long n = n0 + sub; n < n1; n += 4) {
        float v = xf[n * 64 + ch];
        sm += v;
        mx = fmaxf(mx, v);
    }
    __shared__ float ssum[256], smax[256];
    ssum[t] = sm;
    smax[t] = mx;
    __syncthreads();
    if (sub == 0) {
        float a = ssum[ch] + ssum[64 + ch] + ssum[128 + ch] + ssum[192 + ch];
        float m = fmaxf(fmaxf(smax[ch], smax[64 + ch]), fmaxf(smax[128 + ch], smax[192 + ch]));
        float cnt = (float)(n1 - n0);
        pooled[g * 194 + ch] = a;
        pooled[g * 194 + 64 + ch] = a / fmaxf(cnt, 1.f);
        pooled[g * 194 + 128 + ch] = m;
    }
    if (t == 0) {
        pooled[g * 194 + 192] = u[g * 2];
        pooled[g * 194 + 193] = u[g * 2 + 1];
    }
}

// ---------------------------------------------------------------------------
// Readout head (fp32): [G,194]@[194,64] silu, @[64,64] silu, @[64,2]
// ---------------------------------------------------------------------------
__global__ void head_kernel(const float* __restrict__ pooled,
                            const float* __restrict__ LW1, const float* __restrict__ Lb1,
                            const float* __restrict__ LW2, const float* __restrict__ Lb2,
                            const float* __restrict__ LW3, const float* __restrict__ Lb3,
                            float* __restrict__ out, int G) {
    int g = blockIdx.x, t = threadIdx.x;
    __shared__ float pl[194];
    __shared__ float hl[64];
    for (int k = t; k < 194; k += 64) pl[k] = pooled[g * 194 + k];
    __syncthreads();
    float a = Lb1[t];
    for (int k = 0; k < 194; k++) a += pl[k] * LW1[k * 64 + t];
    a = a / (1.0f + __expf(-a));
    hl[t] = a;
    __syncthreads();
    float b = Lb2[t];
    for (int k = 0; k < 64; k++) b += hl[k] * LW2[k * 64 + t];
    b = b / (1.0f + __expf(-b));
    __syncthreads();
    hl[t] = b;
    __syncthreads();
    if (t < 2) {
        float c = Lb3[t];
        for (int k = 0; k < 64; k++) c += hl[k] * LW3[k * 2 + t];
        out[g * 2 + t] = c;
    }
}

// ---------------------------------------------------------------------------
extern "C" void kernel_launch(void* const* d_in, const int* in_sizes, int n_in,
                              void* d_out, int out_size, void* d_ws, size_t ws_size,
                              hipStream_t stream) {
    const float* x   = (const float*)d_in[0];
    const float* u   = (const float*)d_in[1];
    const int*   ei  = (const int*)d_in[2];
    const float* W1  = (const float*)d_in[4];
    const float* b1  = (const float*)d_in[5];
    const float* W2  = (const float*)d_in[6];
    const float* b2  = (const float*)d_in[7];
    const float* W3  = (const float*)d_in[8];
    const float* b3  = (const float*)d_in[9];
    const float* LW1 = (const float*)d_in[10];
    const float* Lb1 = (const float*)d_in[11];
    const float* LW2 = (const float*)d_in[12];
    const float* Lb2 = (const float*)d_in[13];
    const float* LW3 = (const float*)d_in[14];
    const float* Lb3 = (const float*)d_in[15];

    const int N = in_sizes[0] / 64;
    const int G = in_sizes[1] / 2;
    const int E = in_sizes[2] / 2;
    const int L = in_sizes[4] / (126 * 128);

    char* ws = (char*)d_ws;
    size_t off = 0;
    auto alloc = [&](size_t bytes) -> char* {
        char* p = ws + off;
        off += (bytes + 511) & ~(size_t)511;
        return p;
    };
    f16*    PQ     = (f16*)alloc((size_t)N * 256 * 2);
    float4* C      = (float4*)alloc((size_t)N * 16);
    float*  x1     = (float*)alloc((size_t)N * 64 * 4);
    float*  x2     = (float*)alloc((size_t)N * 64 * 4);
    int*    srcs   = (int*)alloc((size_t)E * 4);
    int*    dsts   = (int*)alloc((size_t)E * 4);
    int*    deg    = (int*)alloc((size_t)N * 4);
    int*    rowst  = (int*)alloc((size_t)N * 4);
    int*    cursor = (int*)alloc((size_t)N * 4);
    int*    bsum   = (int*)alloc(4096);
    int*    boff   = (int*)alloc(4096);
    f16*    B1T    = (f16*)alloc((size_t)L * 256 * 64 * 2);
    f16*    W2T    = (f16*)alloc((size_t)L * 128 * 128 * 2);
    f16*    W3T    = (f16*)alloc((size_t)L * 64 * 128 * 2);
    f16*    w1c    = (f16*)alloc((size_t)L * 128 * 2);
    float*  pooled = (float*)alloc((size_t)G * 194 * 4);
    (void)ws_size;
    (void)n_in;
    (void)out_size;

    hipMemsetAsync(deg, 0, (size_t)N * 4, stream);
    hipMemsetAsync(cursor, 0, (size_t)N * 4, stream);
    hipMemsetAsync(x1, 0, (size_t)N * 64 * 4, stream);
    hipMemsetAsync(x2, 0, (size_t)N * 64 * 4, stream);

    {
        int total = L * (16384 + 16384 + 8192 + 128);
        prep_kernel<<<(total + 255) / 256, 256, 0, stream>>>(W1, W2, W3, B1T, W2T, W3T, w1c, L, total);
    }
    hist_kernel<<<(E + 255) / 256, 256, 0, stream>>>(ei, deg, E);
    int NB = (N + 255) / 256;
    scan_part<<<NB, 256, 0, stream>>>(deg, bsum, N);
    scan_mid<<<1, 512, 0, stream>>>(bsum, boff, NB);
    scan_final<<<NB, 256, 0, stream>>>(deg, boff, rowst, N);
    scatter_kernel<<<(E + 255) / 256, 256, 0, stream>>>(ei, rowst, cursor, srcs, dsts, E);

    const float* xcur = x;
    const int wtiles = (E + 15) / 16;
    const int ntiles_node = (N + 63) / 64;
    for (int l = 0; l < L; l++) {
        node_kernel<<<768, 256, 0, stream>>>(xcur, B1T + (size_t)l * 16384, b1 + l * 128,
                                             PQ, C, N, ntiles_node);
        float* xo = (l & 1) ? x2 : x1;
        edge_kernel<<<512, 256, 0, stream>>>(PQ, C, srcs, dsts,
                                             W2T + (size_t)l * 16384, W3T + (size_t)l * 8192,
                                             w1c + l * 128, b2 + l * 128, b3 + l * 64,
                                             xo, E, wtiles);
        xcur = xo;
    }
    pool_kernel<<<G, 256, 0, stream>>>(xcur, u, pooled, N, G);
    head_kernel<<<G, 64, 0, stream>>>(pooled, LW1, Lb1, LW2, Lb2, LW3, Lb3, (float*)d_out, G);
}